// Round 7
// baseline (296.533 us; speedup 1.0000x reference)
//
#include <hip/hip_runtime.h>

// e3nn fully-connected tensor product, v10: v4 byte-for-byte EXCEPT the weight
// stage shrinks 32 KB -> 16 KB (8-u quarters), 2-buffer ring = 32 KB LDS/block.
// v4's occupancy was LDS-bound (64 KB/block -> 2 blocks/CU) while VGPR=128
// would allow 4 waves/SIMD; at 32 KB LDS the same code fits 4 blocks/CU.
// NO forced launch-bounds change (v6/v8's (256,3) capped VGPR at 84 -> spill;
// that was the directive's fault, not the geometry's). Sync stays v4's proven
// single __syncthreads per stage (v7 showed counted vmcnt is equivalent).

typedef _Float16 f16;
typedef f16 f16x8 __attribute__((ext_vector_type(8)));
typedef float f32x16 __attribute__((ext_vector_type(16)));

#define MFMA32(a, b, c) __builtin_amdgcn_mfma_f32_32x32x16_f16(a, b, c, 0, 0, 0)

// A000 = A011 = A101 = A111 = 1/sqrt(2048); A110 = 1/sqrt(6144)
#define SC_COMMON 0.022097086912079608f
#define SC_110    0.012757759118834242f

// ---------------- weight prep ------------------------------------------------
// ws order: c0=w000, c1=w110, c2=w011, c3=w101, c4=w111 (scales folded).
// B-frag (32x32x16): lane holds B[k=(lane>>5)*8+j][n=lane&31], K-chunk vh.
// idx = ((c*32 + u)*2 + vh)*512 + lane*8 + j
//   element = sc * W[u][ v = vh*16 + (lane>>5)*8 + j ][ w = lane&31 ]
// 16 KB stages: stage s = c*4 + (u>>3), flat offset s*8192 f16 (contiguous).
__global__ void prep_w(const float* __restrict__ w000, const float* __restrict__ w011,
                       const float* __restrict__ w101, const float* __restrict__ w110,
                       const float* __restrict__ w111, f16* __restrict__ wsW)
{
    int flat = blockIdx.x * 256 + threadIdx.x;
    if (flat >= 5 * 32768) return;
    int c    = flat >> 15;
    int r    = flat & 32767;
    int j    = r & 7;
    int lane = (r >> 3) & 63;
    int vh   = (r >> 9) & 1;
    int u    = r >> 10;
    int v = vh * 16 + ((lane >> 5) << 3) + j;
    int w = lane & 31;
    const float* src; float sc;
    switch (c) {
        case 0: src = w000; sc = SC_COMMON; break;
        case 1: src = w110; sc = SC_110;    break;
        case 2: src = w011; sc = SC_COMMON; break;
        case 3: src = w101; sc = SC_COMMON; break;
        default: src = w111; sc = SC_COMMON; break;
    }
    wsW[flat] = (f16)(sc * src[u * 1024 + v * 32 + w]);
}

// ---------------- stage compute ---------------------------------------------
// One stage = 8 u-values (quarter Q of a tensor, u = 8*Q + ul) x 2 vh chunks.
// MODE: 0 = w000 (s*s), 1 = w110 (vec dot), 2 = w011 (p011, 3 acc),
//       3 = w101 (p101, 3 acc), 4 = w111 (cross, 3 acc)
template <int Q, int MODE, int NA>
__device__ __forceinline__ void do_stage(f32x16 (&acc)[NA],
                                         const f16* __restrict__ ldsW,
                                         const f16x8 (&f1g)[4][4],
                                         const f16x8 (&f2g)[4][2], int lane)
{
#pragma unroll
    for (int ul = 0; ul < 8; ++ul) {
#pragma unroll
        for (int vh = 0; vh < 2; ++vh) {
            f16x8 b = *(const f16x8*)(ldsW + ul * 1024 + vh * 512 + lane * 8);
            if constexpr (MODE == 0) {
                f16x8 a = f1g[0][Q][ul] * f2g[0][vh];
                acc[0] = MFMA32(a, b, acc[0]);
            } else if constexpr (MODE == 1) {
                f16x8 a = f1g[1][Q][ul] * f2g[1][vh];
                a += f1g[2][Q][ul] * f2g[2][vh];
                a += f1g[3][Q][ul] * f2g[3][vh];
                acc[0] = MFMA32(a, b, acc[0]);
            } else if constexpr (MODE == 2) {
#pragma unroll
                for (int j = 0; j < 3; ++j) {
                    f16x8 a = f1g[0][Q][ul] * f2g[1 + j][vh];
                    acc[j] = MFMA32(a, b, acc[j]);
                }
            } else if constexpr (MODE == 3) {
#pragma unroll
                for (int j = 0; j < 3; ++j) {
                    f16x8 a = f1g[1 + j][Q][ul] * f2g[0][vh];
                    acc[j] = MFMA32(a, b, acc[j]);
                }
            } else {
                // cross: k0:(i=1,j=2)->arrs(2,3); k1:(2,0)->(3,1); k2:(0,1)->(1,2)
#pragma unroll
                for (int k = 0; k < 3; ++k) {
                    constexpr int PP[3] = {2, 3, 1};
                    constexpr int QQ[3] = {3, 1, 2};
                    f16x8 a = f1g[PP[k]][Q][ul] * f2g[QQ[k]][vh]
                            - f1g[QQ[k]][Q][ul] * f2g[PP[k]][vh];
                    acc[k] = MFMA32(a, b, acc[k]);
                }
            }
        }
    }
}

__global__ __launch_bounds__(256, 2)
void tp_main(const float* __restrict__ x1, const float* __restrict__ x2,
             const f16* __restrict__ wsW, float* __restrict__ out)
{
    __shared__ __align__(16) f16 ldsW[2][8192];  // 32 KB: 2-buffer, 16 KB stages

    const int tid = threadIdx.x, lane = tid & 63, wv = tid >> 6;
    const int rowBase = blockIdx.x * 128 + wv * 32;
    const int mrow = lane & 31;          // this lane's row (A and C/D)
    const int half = lane >> 5;          // k-group
    const int klo = half * 8;
    const float4* x1r4 = (const float4*)(x1 + (size_t)(rowBase + mrow) * 128);
    const float4* x2r4 = (const float4*)(x2 + (size_t)(rowBase + mrow) * 128);

    // stage s in [0,20): 16 KB slice s of wsW -> buffer s&1 (4 x 4 KB chunks)
    auto issue = [&](int s) {
        const f16* src = wsW + (size_t)s * 8192;
        f16* dst = &ldsW[s & 1][0];
#pragma unroll
        for (int it = 0; it < 4; ++it) {
            int o = (it * 256 + tid) * 8;
            __builtin_amdgcn_global_load_lds(
                (const __attribute__((address_space(1))) void*)(src + o),
                (__attribute__((address_space(3))) void*)(dst + o), 16, 0, 0);
        }
    };

    issue(0);  // stage 0 DMA in flight during the whole prologue

    // ---- f1: all 128 features of my row, f16, [arr][quarter][ul] ----
    f16x8 f1g[4][4];
    {
        float b0[32];
#pragma unroll
        for (int g = 0; g < 8; ++g) ((float4*)b0)[g] = x1r4[g];
#pragma unroll
        for (int g = 0; g < 4; ++g)
#pragma unroll
            for (int j = 0; j < 8; ++j) f1g[0][g][j] = (f16)b0[g * 8 + j];
        float b1[96];
#pragma unroll
        for (int g = 0; g < 24; ++g) ((float4*)b1)[g] = x1r4[8 + g];
#pragma unroll
        for (int i = 0; i < 3; ++i)
#pragma unroll
            for (int g = 0; g < 4; ++g)
#pragma unroll
                for (int j = 0; j < 8; ++j)
                    f1g[1 + i][g][j] = (f16)b1[3 * (g * 8 + j) + i];
    }

    // ---- f2: my row's k-slice: v = vh*16 + klo + j, [arr][vh] ----
    f16x8 f2g[4][2];
    {
        float c0[16];
#pragma unroll
        for (int g = 0; g < 2; ++g) ((float4*)c0)[g]     = x2r4[klo / 4 + g];
#pragma unroll
        for (int g = 0; g < 2; ++g) ((float4*)c0)[2 + g] = x2r4[4 + klo / 4 + g];
#pragma unroll
        for (int vh = 0; vh < 2; ++vh)
#pragma unroll
            for (int j = 0; j < 8; ++j) f2g[0][vh][j] = (f16)c0[vh * 8 + j];
        // vec spans: floats [32+3*klo, +24) and [80+3*klo, +24), both 16B-aligned
        float c1[48];
        const int base1 = (32 + 3 * klo) / 4;
#pragma unroll
        for (int g = 0; g < 6; ++g) ((float4*)c1)[g]     = x2r4[base1 + g];
#pragma unroll
        for (int g = 0; g < 6; ++g) ((float4*)c1)[6 + g] = x2r4[base1 + 12 + g];
#pragma unroll
        for (int i = 0; i < 3; ++i)
#pragma unroll
            for (int vh = 0; vh < 2; ++vh)
#pragma unroll
                for (int j = 0; j < 8; ++j)
                    f2g[1 + i][vh][j] = (f16)c1[vh * 24 + 3 * j + i];
    }

    __syncthreads();  // stage 0 landed (barrier drains vmcnt for all waves)

    // Per stage s: issue(s+1) into buf (s+1)&1 (WAR-safe: that buffer's reads
    // finished before the PREVIOUS barrier), compute buf s&1, barrier (drains
    // vmcnt -> stage s+1 data visible for next iteration).

    // ================= out0: c0 (mode 0) + c1 (mode 1) =================
    {
        f32x16 acc[1] = {};
        issue(1); do_stage<0, 0>(acc, ldsW[0], f1g, f2g, lane); __syncthreads();
        issue(2); do_stage<1, 0>(acc, ldsW[1], f1g, f2g, lane); __syncthreads();
        issue(3); do_stage<2, 0>(acc, ldsW[0], f1g, f2g, lane); __syncthreads();
        issue(4); do_stage<3, 0>(acc, ldsW[1], f1g, f2g, lane); __syncthreads();
        issue(5); do_stage<0, 1>(acc, ldsW[0], f1g, f2g, lane); __syncthreads();
        issue(6); do_stage<1, 1>(acc, ldsW[1], f1g, f2g, lane); __syncthreads();
        issue(7); do_stage<2, 1>(acc, ldsW[0], f1g, f2g, lane); __syncthreads();
        issue(8); do_stage<3, 1>(acc, ldsW[1], f1g, f2g, lane); __syncthreads();
        // out0 stores issued at the start of stage 8 (after its barrier), so
        // their latency overlaps stage-8 compute.
        issue(9);
#pragma unroll
        for (int reg = 0; reg < 16; ++reg) {
            int r = (reg & 3) + 8 * (reg >> 2) + 4 * half;
            out[(size_t)(rowBase + r) * 224 + mrow] = acc[0][reg];
        }
    }
    // ================= out1: c2 (mode 2) + c3 (mode 3) =================
    {
        f32x16 acc[3] = {};
        /* issue(9) done */ do_stage<0, 2>(acc, ldsW[0], f1g, f2g, lane); __syncthreads();
        issue(10); do_stage<1, 2>(acc, ldsW[1], f1g, f2g, lane); __syncthreads();
        issue(11); do_stage<2, 2>(acc, ldsW[0], f1g, f2g, lane); __syncthreads();
        issue(12); do_stage<3, 2>(acc, ldsW[1], f1g, f2g, lane); __syncthreads();
        issue(13); do_stage<0, 3>(acc, ldsW[0], f1g, f2g, lane); __syncthreads();
        issue(14); do_stage<1, 3>(acc, ldsW[1], f1g, f2g, lane); __syncthreads();
        issue(15); do_stage<2, 3>(acc, ldsW[0], f1g, f2g, lane); __syncthreads();
        issue(16); do_stage<3, 3>(acc, ldsW[1], f1g, f2g, lane); __syncthreads();
        issue(17);
#pragma unroll
        for (int reg = 0; reg < 16; ++reg) {
            int r = (reg & 3) + 8 * (reg >> 2) + 4 * half;
            size_t base = (size_t)(rowBase + r) * 224 + 32 + 3 * mrow;
            out[base + 0] = acc[0][reg];
            out[base + 1] = acc[1][reg];
            out[base + 2] = acc[2][reg];
        }
    }
    // ================= out2: c4 (mode 4) =================
    {
        f32x16 acc[3] = {};
        /* issue(17) done */ do_stage<0, 4>(acc, ldsW[0], f1g, f2g, lane); __syncthreads();
        issue(18); do_stage<1, 4>(acc, ldsW[1], f1g, f2g, lane); __syncthreads();
        issue(19); do_stage<2, 4>(acc, ldsW[0], f1g, f2g, lane); __syncthreads();
                   do_stage<3, 4>(acc, ldsW[1], f1g, f2g, lane);
#pragma unroll
        for (int reg = 0; reg < 16; ++reg) {
            int r = (reg & 3) + 8 * (reg >> 2) + 4 * half;
            size_t base = (size_t)(rowBase + r) * 224 + 128 + 3 * mrow;
            out[base + 0] = acc[0][reg];
            out[base + 1] = acc[1][reg];
            out[base + 2] = acc[2][reg];
        }
    }
}

// ---------------- launch -----------------------------------------------------
extern "C" void kernel_launch(void* const* d_in, const int* in_sizes, int n_in,
                              void* d_out, int out_size, void* d_ws, size_t ws_size,
                              hipStream_t stream)
{
    const float* x1   = (const float*)d_in[0];
    const float* x2   = (const float*)d_in[1];
    const float* w000 = (const float*)d_in[2];
    const float* w011 = (const float*)d_in[3];
    const float* w101 = (const float*)d_in[4];
    const float* w110 = (const float*)d_in[5];
    const float* w111 = (const float*)d_in[6];
    float* out = (float*)d_out;
    f16* wsW = (f16*)d_ws;  // 5 * 32768 f16 = 320 KB

    hipLaunchKernelGGL(prep_w, dim3(640), dim3(256), 0, stream,
                       w000, w011, w101, w110, w111, wsW);

    int n = in_sizes[0] / 128;  // 131072 rows
    hipLaunchKernelGGL(tp_main, dim3(n / 128), dim3(256), 0, stream,
                       x1, x2, wsW, out);
}